// Round 17
// baseline (259.613 us; speedup 1.0000x reference)
//
#include <hip/hip_runtime.h>
#include <hip/hip_bf16.h>
#include <stdint.h>

// AWQ GEMM: out[2048,11008](f32) = x[2048,4096](f32,f16-valued) @ dequant4(...) + bias
// Round 17: 4-phase counted-load schedule (T3/T4/T5) on r14's DMA structure.
//  K1: X f32->f16 pre-swizzled (r14 layout) into d_ws.
//  K2: per K-iter, 4 phases {ds_read frags || 1/4 B-dequant chunk -> raw s_barrier
//      -> setprio(1) -> 8 MFMA -> setprio(0)}; A-DMA (global_load_lds) issued at
//      phase 0 stays IN FLIGHT across the 3 raw barriers (no auto vmcnt drain),
//      drains once at the iter-end __syncthreads. QW raws prefetched 1 iter ahead
//      (2 reg sets, static alternation); scales/zeros 2-iter pipeline.
//  r10 failed because reg-staged A forced vmcnt drains every phase; the DMA path
//  is what makes loads span barriers (the m218 mechanism).

constexpr int TOKENS = 2048;
constexpr int IN_F   = 4096;
constexpr int OUT_F  = 11008;
constexpr int PCOLS  = OUT_F / 8;   // 1376
constexpr int BM = 256, BN = 128, BK = 64;
constexpr int NKT    = IN_F / BK;   // 64
constexpr int NTILES = OUT_F / BN;  // 86
constexpr int ABYTES = BM * BK * 2; // 32768 per buffer
constexpr int BBYTES = BN * BK * 2; // 16384 per buffer
constexpr int LDSTOT = 2 * ABYTES + 2 * BBYTES; // 98304
constexpr size_t XSW_BYTES = (size_t)TOKENS * IN_F * 2; // 16 MB

typedef _Float16 h2 __attribute__((ext_vector_type(2)));
typedef _Float16 h8 __attribute__((ext_vector_type(8)));
typedef float f32x4  __attribute__((ext_vector_type(4)));

__device__ __forceinline__ h2 pkh2(float a, float b) {
    return __builtin_bit_cast(h2, __builtin_amdgcn_cvt_pkrtz(a, b));
}
__device__ __forceinline__ unsigned int pk2(float a, float b) {
    return __builtin_bit_cast(unsigned int, __builtin_amdgcn_cvt_pkrtz(a, b));
}
__device__ __forceinline__ void gld_lds16(const void* g, void* l) {
    __builtin_amdgcn_global_load_lds(
        (const __attribute__((address_space(1))) void*)g,
        (__attribute__((address_space(3))) void*)l,
        16, 0, 0);
}

// ---------------- K1: convert + pre-swizzle X (r14 layout) ----------------
__global__ __launch_bounds__(256)
void x_convert_kernel(const float* __restrict__ X, unsigned short* __restrict__ Xsw)
{
    // g = row*512 + kt*8 + c ; 16B chunk c of (row,kt) holds k-octet c^(row&7)
    const int g   = blockIdx.x * 256 + threadIdx.x;
    const int c   = g & 7;
    const int kt  = (g >> 3) & 63;
    const int row = g >> 9;
    const float* src = X + (size_t)row * IN_F + kt * 64 + ((c ^ (row & 7)) * 8);
    float4 v0 = *(const float4*)(src);
    float4 v1 = *(const float4*)(src + 4);
    uint4 u;
    u.x = pk2(v0.x, v0.y);
    u.y = pk2(v0.z, v0.w);
    u.z = pk2(v1.x, v1.y);
    u.w = pk2(v1.z, v1.w);
    *(uint4*)(Xsw + (size_t)g * 8) = u;
}

// ---------------- K2: 4-phase GEMM ----------------
__global__ __launch_bounds__(512, 2)
void awq_gemm_p4_kernel(const unsigned short* __restrict__ Xsw,
                        const int*   __restrict__ QW,
                        const int*   __restrict__ QZ,
                        const float* __restrict__ S,
                        const float* __restrict__ BIAS,
                        float*       __restrict__ O)
{
    // A buf b: [256 rows][128B] at b*32768 ; B buf b: [128 cols][128B] at 65536+b*16384
    // A: slot c of row r holds k-octet c^(r&7) ; B: k-octet o of col n at o^(n&7)^((n>>3)&7)
    extern __shared__ unsigned char smem[];

    const int t    = threadIdx.x;
    const int lane = t & 63;
    const int w    = t >> 6;      // 0..7
    const int wm   = w >> 1;      // 0..3 (row block of 64)
    const int wn   = w & 1;       // 0..1 (col block of 64)
    const int l15 = lane & 15, l45 = lane >> 4, l7 = lane & 7, l3 = (lane >> 3) & 1;

    // XCD mapping: XCD x (= bid&7) owns mtile x; sweeps all 86 ntiles. 688 = 8*86.
    const int bid   = blockIdx.x;
    const int mtile = bid & 7;
    const int ntile = bid >> 3;
    const int m0 = mtile * BM;
    const int n0 = ntile * BN;
    const int P0 = n0 >> 3;

    // ---- A staging via DMA (r14-verified) ----
    const unsigned char* XswB = (const unsigned char*)Xsw;
    auto stage_A_dma = [&](int buf, int kt) {
        unsigned char* ab = smem + buf * ABYTES;
#pragma unroll
        for (int i = 0; i < 4; ++i) {
            const int row_g = m0 + i * 64 + (t >> 3);
            const unsigned char* src = XswB + (((size_t)row_g * 64 + kt) * 8 + (t & 7)) * 16;
            gld_lds16(src, ab + i * 8192 + w * 1024);
        }
    };

    // ---- B staging: thread covers packed col pcol = t&15, k-pair 2kd, 2kd+1 ----
    const int pcol = t & 15;
    const int kd   = t >> 4;         // 0..31
    const int pc7  = pcol & 7;
    const int ob   = kd >> 2;        // k-octet
    const int sub  = (kd & 3) * 4;   // byte offset within 16B slot
    const int* qwb = QW + (size_t)(2 * kd) * PCOLS + P0 + pcol;
    const unsigned int* qzc = (const unsigned int*)QZ + P0 + pcol;
    const float* scol = S + n0 + pcol * 8;

    constexpr int SH[8]  = {0, 16, 4, 20, 8, 24, 12, 28}; // shift of logical nibble j
    constexpr int JLO[4] = {0, 4, 1, 5};                  // low-nibble j of byte b

    h2 spk[8], zpk[8];
    unsigned int zraw_n; float4 sv0, sv1;

    auto load_group = [&](int g) {
        zraw_n = qzc[(size_t)g * PCOLS];
        sv0 = *(const float4*)(scol + (size_t)g * OUT_F);
        sv1 = *(const float4*)(scol + (size_t)g * OUT_F + 4);
    };
    auto compute_group = [&]() {
        const float sf[8] = {sv0.x, sv0.y, sv0.z, sv0.w, sv1.x, sv1.y, sv1.z, sv1.w};
#pragma unroll
        for (int j = 0; j < 8; ++j) {
            float zb = 1024.0f + (float)((zraw_n >> SH[j]) & 15u);  // exact in f16
            spk[j] = pkh2(sf[j], sf[j]);
            zpk[j] = pkh2(zb, zb);
        }
    };
    auto load_raws_to = [&](unsigned int (&rw)[2], int kt) {
        const size_t off = (size_t)kt * BK * PCOLS;
        rw[0] = (unsigned int)qwb[off];
        rw[1] = (unsigned int)qwb[off + PCOLS];
    };
    auto stage_chunk = [&](unsigned char* bb, const unsigned int (&rw)[2], int b) {
        const int jl = JLO[b], jh = jl + 2;
        unsigned int d  = __builtin_amdgcn_perm(rw[1], rw[0],
                             (unsigned int)(((4 + b) << 16) | b));
        unsigned int lo = (d & 0x000F000Fu) | 0x64006400u;         // (1024+q), j=jl
        unsigned int hi = ((d >> 4) & 0x000F000Fu) | 0x64006400u;  // j=jh
        h2 wl = (__builtin_bit_cast(h2, lo) - zpk[jl]) * spk[jl];  // exact sub, 1 rounding
        h2 wh = (__builtin_bit_cast(h2, hi) - zpk[jh]) * spk[jh];
        const int nl = pcol * 8 + jl, nh = pcol * 8 + jh;
        *(unsigned int*)(bb + nl * 128 + ((ob ^ jl ^ pc7) * 16) + sub) =
            __builtin_bit_cast(unsigned int, wl);
        *(unsigned int*)(bb + nh * 128 + ((ob ^ jh ^ pc7) * 16) + sub) =
            __builtin_bit_cast(unsigned int, wh);
    };

    auto read_a = [&](const unsigned char* ab, int mi, int ks) -> h8 {
        int off = (wm * 64 + mi * 16 + l15) * 128 + (((ks * 4 + l45) ^ l7) * 16);
        return *(const h8*)(ab + off);
    };
    auto read_b = [&](const unsigned char* bb, int ni, int ks) -> h8 {
        int off = (wn * 64 + ni * 16 + l15) * 128
                + ((((ks * 4 + l45) ^ l7 ^ l3) ^ (2 * ni)) * 16);
        return *(const h8*)(bb + off);
    };

    f32x4 acc[4][4];
#pragma unroll
    for (int mi = 0; mi < 4; ++mi)
#pragma unroll
        for (int ni = 0; ni < 4; ++ni)
            acc[mi][ni] = f32x4{0.f, 0.f, 0.f, 0.f};

    unsigned int rwA[2], rwB[2], rw0[2];

    // ---- prologue: stage tile 0 (A-DMA + B), raws for tile 1, consts g0 ----
    load_raws_to(rw0, 0);
    load_group(0);
    stage_A_dma(0, 0);
    compute_group();                       // consts g0 (tiles 0,1)
    {
        unsigned char* bb0 = smem + 2 * ABYTES;
#pragma unroll
        for (int b = 0; b < 4; ++b) stage_chunk(bb0, rw0, b);
    }
    load_raws_to(rwB, 1);                  // raws for tile 1 (consumed iter 0)
    __syncthreads();

    // ---- one K-iteration: 4 phases; rwC = raws(kt+1), rwN <- raws(kt+2) ----
    auto K_ITER = [&](int kt, unsigned int (&rwC)[2], unsigned int (&rwN)[2]) {
        const int cur = kt & 1;
        const bool nxt = (kt + 1 < NKT);
        const unsigned char* abC = smem + cur * ABYTES;
        const unsigned char* bbC = smem + 2 * ABYTES + cur * BBYTES;
        unsigned char* bbN = smem + 2 * ABYTES + (cur ^ 1) * BBYTES;

        h8 a0, a1, b0, b1, b2, b3;
        auto CL = [&](int mi0) {
            acc[mi0][0]   = __builtin_amdgcn_mfma_f32_16x16x32_f16(a0, b0, acc[mi0][0], 0, 0, 0);
            acc[mi0][1]   = __builtin_amdgcn_mfma_f32_16x16x32_f16(a0, b1, acc[mi0][1], 0, 0, 0);
            acc[mi0][2]   = __builtin_amdgcn_mfma_f32_16x16x32_f16(a0, b2, acc[mi0][2], 0, 0, 0);
            acc[mi0][3]   = __builtin_amdgcn_mfma_f32_16x16x32_f16(a0, b3, acc[mi0][3], 0, 0, 0);
            acc[mi0+1][0] = __builtin_amdgcn_mfma_f32_16x16x32_f16(a1, b0, acc[mi0+1][0], 0, 0, 0);
            acc[mi0+1][1] = __builtin_amdgcn_mfma_f32_16x16x32_f16(a1, b1, acc[mi0+1][1], 0, 0, 0);
            acc[mi0+1][2] = __builtin_amdgcn_mfma_f32_16x16x32_f16(a1, b2, acc[mi0+1][2], 0, 0, 0);
            acc[mi0+1][3] = __builtin_amdgcn_mfma_f32_16x16x32_f16(a1, b3, acc[mi0+1][3], 0, 0, 0);
        };

        // -- phase 0: ks=0, mi 0,1 --
        if (nxt) {
            if ((kt & 1) == 1) compute_group();        // consts for even tile kt+1 (loaded iter kt-1)
            stage_A_dma(cur ^ 1, kt + 1);              // DMA: in flight across phase barriers
            load_raws_to(rwN, kt + 2 < NKT ? kt + 2 : kt + 1);
            if ((kt & 1) == 0 && kt + 4 <= NKT) load_group(kt / 2 + 1);
        }
        b0 = read_b(bbC, 0, 0); b1 = read_b(bbC, 1, 0);
        b2 = read_b(bbC, 2, 0); b3 = read_b(bbC, 3, 0);
        a0 = read_a(abC, 0, 0); a1 = read_a(abC, 1, 0);
        if (nxt) stage_chunk(bbN, rwC, 0);
        __builtin_amdgcn_s_barrier();
        __builtin_amdgcn_s_setprio(1); CL(0); __builtin_amdgcn_s_setprio(0);

        // -- phase 1: ks=0, mi 2,3 (b regs reused) --
        a0 = read_a(abC, 2, 0); a1 = read_a(abC, 3, 0);
        if (nxt) stage_chunk(bbN, rwC, 1);
        __builtin_amdgcn_s_barrier();
        __builtin_amdgcn_s_setprio(1); CL(2); __builtin_amdgcn_s_setprio(0);

        // -- phase 2: ks=1, mi 0,1 --
        b0 = read_b(bbC, 0, 1); b1 = read_b(bbC, 1, 1);
        b2 = read_b(bbC, 2, 1); b3 = read_b(bbC, 3, 1);
        a0 = read_a(abC, 0, 1); a1 = read_a(abC, 1, 1);
        if (nxt) stage_chunk(bbN, rwC, 2);
        __builtin_amdgcn_s_barrier();
        __builtin_amdgcn_s_setprio(1); CL(0); __builtin_amdgcn_s_setprio(0);

        // -- phase 3: ks=1, mi 2,3; iter-end full sync drains DMA + ds_writes --
        a0 = read_a(abC, 2, 1); a1 = read_a(abC, 3, 1);
        if (nxt) stage_chunk(bbN, rwC, 3);
        __builtin_amdgcn_s_setprio(1); CL(2); __builtin_amdgcn_s_setprio(0);
        __syncthreads();
    };

    // ---- main loop: static even/odd raw-set alternation ----
#pragma unroll 1
    for (int kt = 0; kt < NKT; kt += 2) {
        K_ITER(kt,     rwB, rwA);
        K_ITER(kt + 1, rwA, rwB);
    }

    // ---- epilogue: bias + f32 store (C/D: col=lane&15, row=(lane>>4)*4+reg) ----
    const int orow0 = m0 + wm * 64 + l45 * 4;
    const int ocol0 = n0 + wn * 64 + l15;
    float bv[4];
#pragma unroll
    for (int ni = 0; ni < 4; ++ni)
        bv[ni] = BIAS[ocol0 + ni * 16];
#pragma unroll
    for (int mi = 0; mi < 4; ++mi)
#pragma unroll
        for (int ni = 0; ni < 4; ++ni)
#pragma unroll
            for (int r = 0; r < 4; ++r) {
                int row = orow0 + mi * 16 + r;
                int col = ocol0 + ni * 16;
                O[(size_t)row * OUT_F + col] = acc[mi][ni][r] + bv[ni];
            }
}

// ---------------- fallback: r12 kernel (ws too small) ----------------
__global__ __launch_bounds__(512, 2)
void awq_gemm_fb_kernel(const float* __restrict__ X,
                        const int*   __restrict__ QW,
                        const int*   __restrict__ QZ,
                        const float* __restrict__ S,
                        const float* __restrict__ BIAS,
                        float*       __restrict__ O)
{
    __shared__ alignas(16) unsigned char smem[ABYTES + 2 * BBYTES];

    const int t    = threadIdx.x;
    const int lane = t & 63;
    const int w    = t >> 6;
    const int wm   = w >> 1;
    const int wn   = w & 1;
    const int l15 = lane & 15, l45 = lane >> 4, l7 = lane & 7, l3 = (lane >> 3) & 1;

    const int bid   = blockIdx.x;
    const int mtile = bid & 7;
    const int ntile = bid >> 3;
    const int m0 = mtile * BM;
    const int n0 = ntile * BN;
    const int P0 = n0 >> 3;

    const int arow = t >> 3;
    const int aoct = t & 7;
    const int aphys = aoct ^ (arow & 7);
    const float* Xb = X + (size_t)(m0 + arow) * IN_F + aoct * 8;

    float4 areg[4][2];
    auto load_A = [&](int kt) {
#pragma unroll
        for (int i = 0; i < 4; ++i) {
            const float* p = Xb + (size_t)i * 64 * IN_F + kt * BK;
            areg[i][0] = *(const float4*)(p);
            areg[i][1] = *(const float4*)(p + 4);
        }
    };
    auto write_A = [&]() {
        unsigned char* ab = smem;
#pragma unroll
        for (int i = 0; i < 4; ++i) {
            uint4 v;
            v.x = pk2(areg[i][0].x, areg[i][0].y);
            v.y = pk2(areg[i][0].z, areg[i][0].w);
            v.z = pk2(areg[i][1].x, areg[i][1].y);
            v.w = pk2(areg[i][1].z, areg[i][1].w);
            *(uint4*)(ab + (i * 64 + arow) * 128 + aphys * 16) = v;
        }
    };

    const int pcol = t & 15;
    const int kd   = t >> 4;
    const int pc7  = pcol & 7;
    const int ob   = kd >> 2;
    const int sub  = (kd & 3) * 4;
    const int* qwb = QW + (size_t)(2 * kd) * PCOLS + P0 + pcol;
    const unsigned int* qzc = (const unsigned int*)QZ + P0 + pcol;
    const float* scol = S + n0 + pcol * 8;

    constexpr int SH[8]  = {0, 16, 4, 20, 8, 24, 12, 28};
    constexpr int JLO[4] = {0, 4, 1, 5};

    h2 spk[8], zpk[8];
    unsigned int zraw_n; float4 sv0, sv1;
    unsigned int raw0, raw1;

    auto load_group = [&](int g) {
        zraw_n = qzc[(size_t)g * PCOLS];
        sv0 = *(const float4*)(scol + (size_t)g * OUT_F);
        sv1 = *(const float4*)(scol + (size_t)g * OUT_F + 4);
    };
    auto compute_group = [&]() {
        const float sf[8] = {sv0.x, sv0.y, sv0.z, sv0.w, sv1.x, sv1.y, sv1.z, sv1.w};
#pragma unroll
        for (int j = 0; j < 8; ++j) {
            float zb = 1024.0f + (float)((zraw_n >> SH[j]) & 15u);
            spk[j] = pkh2(sf[j], sf[j]);
            zpk[j] = pkh2(zb, zb);
        }
    };
    auto load_raws = [&](int kt) {
        const size_t off = (size_t)kt * BK * PCOLS;
        raw0 = (unsigned int)qwb[off];
        raw1 = (unsigned int)qwb[off + PCOLS];
    };
    auto stage_B = [&](int buf) {
        unsigned char* bb = smem + ABYTES + buf * BBYTES;
#pragma unroll
        for (int b = 0; b < 4; ++b) {
            const int jl = JLO[b], jh = jl + 2;
            unsigned int d  = __builtin_amdgcn_perm(raw1, raw0,
                                 (unsigned int)(((4 + b) << 16) | b));
            unsigned int lo = (d & 0x000F000Fu) | 0x64006400u;
            unsigned int hi = ((d >> 4) & 0x000F000Fu) | 0x64006400u;
            h2 wl = (__builtin_bit_cast(h2, lo) - zpk[jl]) * spk[jl];
            h2 wh = (__builtin_bit_cast(h2, hi) - zpk[jh]) * spk[jh];
            const int nl = pcol * 8 + jl, nh = pcol * 8 + jh;
            *(unsigned int*)(bb + nl * 128 + ((ob ^ jl ^ pc7) * 16) + sub) =
                __builtin_bit_cast(unsigned int, wl);
            *(unsigned int*)(bb + nh * 128 + ((ob ^ jh ^ pc7) * 16) + sub) =
                __builtin_bit_cast(unsigned int, wh);
        }
    };

    f32x4 acc[4][4];
#pragma unroll
    for (int mi = 0; mi < 4; ++mi)
#pragma unroll
        for (int ni = 0; ni < 4; ++ni)
            acc[mi][ni] = f32x4{0.f, 0.f, 0.f, 0.f};

    auto compute_tile = [&](int buf) {
        const unsigned char* ab = smem;
        const unsigned char* bb = smem + ABYTES + buf * BBYTES;
#pragma unroll
        for (int ks = 0; ks < 2; ++ks) {
            h8 a[4], bf[4];
#pragma unroll
            for (int mi = 0; mi < 4; ++mi) {
                int off = (wm * 64 + mi * 16 + l15) * 128
                        + (((ks * 4 + l45) ^ l7) * 16);
                a[mi] = *(const h8*)(ab + off);
            }
#pragma unroll
            for (int ni = 0; ni < 4; ++ni) {
                int off = (wn * 64 + ni * 16 + l15) * 128
                        + ((((ks * 4 + l45) ^ l7 ^ l3) ^ (2 * ni)) * 16);
                bf[ni] = *(const h8*)(bb + off);
            }
#pragma unroll
            for (int mi = 0; mi < 4; ++mi)
#pragma unroll
                for (int ni = 0; ni < 4; ++ni)
                    acc[mi][ni] = __builtin_amdgcn_mfma_f32_16x16x32_f16(
                        a[mi], bf[ni], acc[mi][ni], 0, 0, 0);
        }
    };

    load_A(0);
    load_raws(0);
    load_group(0);
    compute_group();
    write_A();
    stage_B(0);
    __syncthreads();

#pragma unroll 2
    for (int kt = 0; kt < NKT; ++kt) {
        const int cur = kt & 1;
        if (kt + 1 < NKT) {
            load_A(kt + 1);
            load_raws(kt + 1);
            if (((kt + 1) & 1) == 0) load_group((kt + 1) >> 1);
        }
        compute_tile(cur);
        if (kt + 1 < NKT) {
            if (((kt + 1) & 1) == 0) compute_group();
            stage_B(cur ^ 1);
        }
        __syncthreads();
        if (kt + 1 < NKT) write_A();
        __syncthreads();
    }

    const int orow0 = m0 + wm * 64 + l45 * 4;
    const int ocol0 = n0 + wn * 64 + l15;
    float bv[4];
#pragma unroll
    for (int ni = 0; ni < 4; ++ni)
        bv[ni] = BIAS[ocol0 + ni * 16];
#pragma unroll
    for (int mi = 0; mi < 4; ++mi)
#pragma unroll
        for (int ni = 0; ni < 4; ++ni)
#pragma unroll
            for (int r = 0; r < 4; ++r) {
                int row = orow0 + mi * 16 + r;
                int col = ocol0 + ni * 16;
                O[(size_t)row * OUT_F + col] = acc[mi][ni][r] + bv[ni];
            }
}

extern "C" void kernel_launch(void* const* d_in, const int* in_sizes, int n_in,
                              void* d_out, int out_size, void* d_ws, size_t ws_size,
                              hipStream_t stream) {
    const float* X  = (const float*)d_in[0];
    const int*   QW = (const int*)d_in[1];
    const int*   QZ = (const int*)d_in[2];
    const float* S  = (const float*)d_in[3];
    const float* Bi = (const float*)d_in[4];
    float*       O  = (float*)d_out;

    if (ws_size >= XSW_BYTES) {
        unsigned short* Xsw = (unsigned short*)d_ws;
        x_convert_kernel<<<dim3(TOKENS * IN_F / 8 / 256), dim3(256), 0, stream>>>(X, Xsw);
        awq_gemm_p4_kernel<<<dim3(8 * NTILES), dim3(512), LDSTOT, stream>>>(
            Xsw, QW, QZ, S, Bi, O);
    } else {
        awq_gemm_fb_kernel<<<dim3(8 * NTILES), dim3(512), 0, stream>>>(X, QW, QZ, S, Bi, O);
    }
}

// Round 18
// 237.881 us; speedup vs baseline: 1.0914x; 1.0914x over previous
//
#include <hip/hip_runtime.h>
#include <hip/hip_bf16.h>
#include <stdint.h>

// AWQ GEMM: out[2048,11008](f32) = x[2048,4096](f32,f16-valued) @ dequant4(...) + bias
// Round 18: TRUE T4 (counted vmcnt, never drain) on r14's DMA structure.
//  - A: 3-buffer DMA pipeline (iter kt issues A(kt+2)); LDS 3x32K + 2x16K = 128 KB.
//  - Iter-end: s_waitcnt vmcnt(6) lgkmcnt(0) + raw s_barrier. vmcnt(6) is safe:
//    every steady iter issues >=6 vmem ops (DMA 4 + raws 2 [+2 group]) strictly
//    after A(kt+1)'s 4 DMA loads (separated by the previous "memory" barrier),
//    so "all but newest 6 complete" implies A(kt+1) landed. Tail iter uses vmcnt(0).
//  - r17's mistake: __syncthreads drained vmcnt(0) every iter (T3 without T4 = the
//    m218 null). No phase split this time (hurt twice: r10, r17).
// Fallback (ws too small): r12 single-kernel path.

constexpr int TOKENS = 2048;
constexpr int IN_F   = 4096;
constexpr int OUT_F  = 11008;
constexpr int PCOLS  = OUT_F / 8;   // 1376
constexpr int BM = 256, BN = 128, BK = 64;
constexpr int NKT    = IN_F / BK;   // 64
constexpr int NTILES = OUT_F / BN;  // 86
constexpr int ABYTES = BM * BK * 2; // 32768 per A buffer (x3)
constexpr int BBYTES = BN * BK * 2; // 16384 per B buffer (x2)
constexpr int BOFF   = 3 * ABYTES;  // 98304
constexpr int LDSTOT = 3 * ABYTES + 2 * BBYTES; // 131072 (m201-proven size)
constexpr size_t XSW_BYTES = (size_t)TOKENS * IN_F * 2; // 16 MB

typedef _Float16 h2 __attribute__((ext_vector_type(2)));
typedef _Float16 h8 __attribute__((ext_vector_type(8)));
typedef float f32x4  __attribute__((ext_vector_type(4)));

__device__ __forceinline__ h2 pkh2(float a, float b) {
    return __builtin_bit_cast(h2, __builtin_amdgcn_cvt_pkrtz(a, b));
}
__device__ __forceinline__ unsigned int pk2(float a, float b) {
    return __builtin_bit_cast(unsigned int, __builtin_amdgcn_cvt_pkrtz(a, b));
}
__device__ __forceinline__ void gld_lds16(const void* g, void* l) {
    __builtin_amdgcn_global_load_lds(
        (const __attribute__((address_space(1))) void*)g,
        (__attribute__((address_space(3))) void*)l,
        16, 0, 0);
}

// ---------------- K1: convert + pre-swizzle X (r14 layout) ----------------
__global__ __launch_bounds__(256)
void x_convert_kernel(const float* __restrict__ X, unsigned short* __restrict__ Xsw)
{
    // g = row*512 + kt*8 + c ; 16B chunk c of (row,kt) holds k-octet c^(row&7)
    const int g   = blockIdx.x * 256 + threadIdx.x;
    const int c   = g & 7;
    const int kt  = (g >> 3) & 63;
    const int row = g >> 9;
    const float* src = X + (size_t)row * IN_F + kt * 64 + ((c ^ (row & 7)) * 8);
    float4 v0 = *(const float4*)(src);
    float4 v1 = *(const float4*)(src + 4);
    uint4 u;
    u.x = pk2(v0.x, v0.y);
    u.y = pk2(v0.z, v0.w);
    u.z = pk2(v1.x, v1.y);
    u.w = pk2(v1.z, v1.w);
    *(uint4*)(Xsw + (size_t)g * 8) = u;
}

// ---------------- K2: counted-vmcnt GEMM ----------------
__global__ __launch_bounds__(512, 2)
void awq_gemm_cv_kernel(const unsigned short* __restrict__ Xsw,
                        const int*   __restrict__ QW,
                        const int*   __restrict__ QZ,
                        const float* __restrict__ S,
                        const float* __restrict__ BIAS,
                        float*       __restrict__ O)
{
    // A buf b (0..2): [256 rows][128B] at b*32768 ; B buf b (0..1) at 98304+b*16384
    // A: slot c of row r holds k-octet c^(r&7) ; B: k-octet o of col n at o^(n&7)^((n>>3)&7)
    extern __shared__ unsigned char smem[];

    const int t    = threadIdx.x;
    const int lane = t & 63;
    const int w    = t >> 6;      // 0..7
    const int wm   = w >> 1;      // 0..3 (row block of 64)
    const int wn   = w & 1;       // 0..1 (col block of 64)
    const int l15 = lane & 15, l45 = lane >> 4, l7 = lane & 7, l3 = (lane >> 3) & 1;

    // XCD mapping: XCD x (= bid&7) owns mtile x; sweeps all 86 ntiles. 688 = 8*86.
    const int bid   = blockIdx.x;
    const int mtile = bid & 7;
    const int ntile = bid >> 3;
    const int m0 = mtile * BM;
    const int n0 = ntile * BN;
    const int P0 = n0 >> 3;

    // ---- A staging via DMA (r14-verified path) ----
    const unsigned char* XswB = (const unsigned char*)Xsw;
    auto stage_A_dma = [&](int buf, int kt) {
        unsigned char* ab = smem + buf * ABYTES;
#pragma unroll
        for (int i = 0; i < 4; ++i) {
            const int row_g = m0 + i * 64 + (t >> 3);
            const unsigned char* src = XswB + (((size_t)row_g * 64 + kt) * 8 + (t & 7)) * 16;
            gld_lds16(src, ab + i * 8192 + w * 1024);
        }
    };

    // ---- B staging: thread covers packed col pcol = t&15, k-pair 2kd, 2kd+1 ----
    const int pcol = t & 15;
    const int kd   = t >> 4;         // 0..31
    const int pc7  = pcol & 7;
    const int ob   = kd >> 2;        // k-octet
    const int sub  = (kd & 3) * 4;   // byte offset within 16B slot
    const int* qwb = QW + (size_t)(2 * kd) * PCOLS + P0 + pcol;
    const unsigned int* qzc = (const unsigned int*)QZ + P0 + pcol;
    const float* scol = S + n0 + pcol * 8;

    constexpr int SH[8]  = {0, 16, 4, 20, 8, 24, 12, 28}; // shift of logical nibble j
    constexpr int JLO[4] = {0, 4, 1, 5};                  // low-nibble j of byte b

    h2 spk[8], zpk[8];
    unsigned int zraw_n; float4 sv0, sv1;

    auto load_group = [&](int g) {
        zraw_n = qzc[(size_t)g * PCOLS];
        sv0 = *(const float4*)(scol + (size_t)g * OUT_F);
        sv1 = *(const float4*)(scol + (size_t)g * OUT_F + 4);
    };
    auto compute_group = [&]() {
        const float sf[8] = {sv0.x, sv0.y, sv0.z, sv0.w, sv1.x, sv1.y, sv1.z, sv1.w};
#pragma unroll
        for (int j = 0; j < 8; ++j) {
            float zb = 1024.0f + (float)((zraw_n >> SH[j]) & 15u);  // exact in f16
            spk[j] = pkh2(sf[j], sf[j]);
            zpk[j] = pkh2(zb, zb);
        }
    };
    auto load_raws_to = [&](unsigned int (&rw)[2], int kt) {
        const size_t off = (size_t)kt * BK * PCOLS;
        rw[0] = (unsigned int)qwb[off];
        rw[1] = (unsigned int)qwb[off + PCOLS];
    };
    auto stage_B = [&](int buf, const unsigned int (&rw)[2]) {
        unsigned char* bb = smem + BOFF + buf * BBYTES;
#pragma unroll
        for (int b = 0; b < 4; ++b) {
            const int jl = JLO[b], jh = jl + 2;
            unsigned int d  = __builtin_amdgcn_perm(rw[1], rw[0],
                                 (unsigned int)(((4 + b) << 16) | b));
            unsigned int lo = (d & 0x000F000Fu) | 0x64006400u;         // (1024+q), j=jl
            unsigned int hi = ((d >> 4) & 0x000F000Fu) | 0x64006400u;  // j=jh
            h2 wl = (__builtin_bit_cast(h2, lo) - zpk[jl]) * spk[jl];  // exact sub, 1 rounding
            h2 wh = (__builtin_bit_cast(h2, hi) - zpk[jh]) * spk[jh];
            const int nl = pcol * 8 + jl, nh = pcol * 8 + jh;
            *(unsigned int*)(bb + nl * 128 + ((ob ^ jl ^ pc7) * 16) + sub) =
                __builtin_bit_cast(unsigned int, wl);
            *(unsigned int*)(bb + nh * 128 + ((ob ^ jh ^ pc7) * 16) + sub) =
                __builtin_bit_cast(unsigned int, wh);
        }
    };

    f32x4 acc[4][4];
#pragma unroll
    for (int mi = 0; mi < 4; ++mi)
#pragma unroll
        for (int ni = 0; ni < 4; ++ni)
            acc[mi][ni] = f32x4{0.f, 0.f, 0.f, 0.f};

    auto compute_tile = [&](int abuf, int bbuf) {
        const unsigned char* ab = smem + abuf * ABYTES;
        const unsigned char* bb = smem + BOFF + bbuf * BBYTES;
#pragma unroll
        for (int ks = 0; ks < 2; ++ks) {
            h8 a[4], bf[4];
#pragma unroll
            for (int mi = 0; mi < 4; ++mi) {
                int off = (wm * 64 + mi * 16 + l15) * 128
                        + (((ks * 4 + l45) ^ l7) * 16);          // row&7 == l7
                a[mi] = *(const h8*)(ab + off);
            }
#pragma unroll
            for (int ni = 0; ni < 4; ++ni) {
                int off = (wn * 64 + ni * 16 + l15) * 128
                        + ((((ks * 4 + l45) ^ l7 ^ l3) ^ (2 * ni)) * 16); // n&7==l7
                bf[ni] = *(const h8*)(bb + off);
            }
#pragma unroll
            for (int mi = 0; mi < 4; ++mi)
#pragma unroll
                for (int ni = 0; ni < 4; ++ni)
                    acc[mi][ni] = __builtin_amdgcn_mfma_f32_16x16x32_f16(
                        a[mi], bf[ni], acc[mi][ni], 0, 0, 0);
        }
    };

    unsigned int rwA[2], rwB[2], rw0[2];

    // ---- prologue: DMA A(0)->buf0, A(1)->buf1; B tile 0 -> Bbuf0; raws(1) -> rwB ----
    stage_A_dma(0, 0);
    stage_A_dma(1, 1);
    load_raws_to(rw0, 0);
    load_raws_to(rwB, 1);
    load_group(0);
    compute_group();                       // consts g0 (tiles 0,1)
    stage_B(0, rw0);
    asm volatile("s_waitcnt vmcnt(0) lgkmcnt(0)" ::: "memory");
    __builtin_amdgcn_s_barrier();

    // ---- one K-iteration: counted vmcnt, single raw barrier ----
    // rwC = raws(kt+1) [consumed this iter], rwN <- raws(kt+2)
    auto K_ITER = [&](int kt, unsigned int (&rwC)[2], unsigned int (&rwN)[2]) {
        const bool has1 = (kt + 1 < NKT);
        const bool has2 = (kt + 2 < NKT);
        if (has2) {
            stage_A_dma((kt + 2) % 3, kt + 2);      // 4 vmem, stays in flight
            load_raws_to(rwN, kt + 2);              // 2 vmem
            if (((kt + 2) & 1) == 0) load_group((kt + 2) >> 1);  // 2 vmem (even kt)
        }
        compute_tile(kt % 3, kt & 1);
        if (has1) {
            if (((kt + 1) & 1) == 0) compute_group();
            stage_B((kt + 1) & 1, rwC);
        }
        if (has1) {
            if (has2) {
                // >=6 vmem ops of THIS iter are provably newer than A(kt+1)'s DMA
                // (separated by previous iter's "memory" barrier) -> vmcnt(6) safe.
                asm volatile("s_waitcnt vmcnt(6) lgkmcnt(0)" ::: "memory");
            } else {
                asm volatile("s_waitcnt vmcnt(0) lgkmcnt(0)" ::: "memory");
            }
            __builtin_amdgcn_s_barrier();
        }
    };

    // ---- main loop: static even/odd raw-set alternation ----
#pragma unroll 1
    for (int kt = 0; kt < NKT; kt += 2) {
        K_ITER(kt,     rwB, rwA);
        K_ITER(kt + 1, rwA, rwB);
    }

    // ---- epilogue: bias + f32 store (C/D: col=lane&15, row=(lane>>4)*4+reg) ----
    const int orow0 = m0 + wm * 64 + l45 * 4;
    const int ocol0 = n0 + wn * 64 + l15;
    float bv[4];
#pragma unroll
    for (int ni = 0; ni < 4; ++ni)
        bv[ni] = BIAS[ocol0 + ni * 16];
#pragma unroll
    for (int mi = 0; mi < 4; ++mi)
#pragma unroll
        for (int ni = 0; ni < 4; ++ni)
#pragma unroll
            for (int r = 0; r < 4; ++r) {
                int row = orow0 + mi * 16 + r;
                int col = ocol0 + ni * 16;
                O[(size_t)row * OUT_F + col] = acc[mi][ni][r] + bv[ni];
            }
}

// ---------------- fallback: r12 kernel (ws too small) ----------------
__global__ __launch_bounds__(512, 2)
void awq_gemm_fb_kernel(const float* __restrict__ X,
                        const int*   __restrict__ QW,
                        const int*   __restrict__ QZ,
                        const float* __restrict__ S,
                        const float* __restrict__ BIAS,
                        float*       __restrict__ O)
{
    __shared__ alignas(16) unsigned char smem[ABYTES + 2 * BBYTES];

    const int t    = threadIdx.x;
    const int lane = t & 63;
    const int w    = t >> 6;
    const int wm   = w >> 1;
    const int wn   = w & 1;
    const int l15 = lane & 15, l45 = lane >> 4, l7 = lane & 7, l3 = (lane >> 3) & 1;

    const int bid   = blockIdx.x;
    const int mtile = bid & 7;
    const int ntile = bid >> 3;
    const int m0 = mtile * BM;
    const int n0 = ntile * BN;
    const int P0 = n0 >> 3;

    const int arow = t >> 3;
    const int aoct = t & 7;
    const int aphys = aoct ^ (arow & 7);
    const float* Xb = X + (size_t)(m0 + arow) * IN_F + aoct * 8;

    float4 areg[4][2];
    auto load_A = [&](int kt) {
#pragma unroll
        for (int i = 0; i < 4; ++i) {
            const float* p = Xb + (size_t)i * 64 * IN_F + kt * BK;
            areg[i][0] = *(const float4*)(p);
            areg[i][1] = *(const float4*)(p + 4);
        }
    };
    auto write_A = [&]() {
        unsigned char* ab = smem;
#pragma unroll
        for (int i = 0; i < 4; ++i) {
            uint4 v;
            v.x = pk2(areg[i][0].x, areg[i][0].y);
            v.y = pk2(areg[i][0].z, areg[i][0].w);
            v.z = pk2(areg[i][1].x, areg[i][1].y);
            v.w = pk2(areg[i][1].z, areg[i][1].w);
            *(uint4*)(ab + (i * 64 + arow) * 128 + aphys * 16) = v;
        }
    };

    const int pcol = t & 15;
    const int kd   = t >> 4;
    const int pc7  = pcol & 7;
    const int ob   = kd >> 2;
    const int sub  = (kd & 3) * 4;
    const int* qwb = QW + (size_t)(2 * kd) * PCOLS + P0 + pcol;
    const unsigned int* qzc = (const unsigned int*)QZ + P0 + pcol;
    const float* scol = S + n0 + pcol * 8;

    constexpr int SH[8]  = {0, 16, 4, 20, 8, 24, 12, 28};
    constexpr int JLO[4] = {0, 4, 1, 5};

    h2 spk[8], zpk[8];
    unsigned int zraw_n; float4 sv0, sv1;
    unsigned int raw0, raw1;

    auto load_group = [&](int g) {
        zraw_n = qzc[(size_t)g * PCOLS];
        sv0 = *(const float4*)(scol + (size_t)g * OUT_F);
        sv1 = *(const float4*)(scol + (size_t)g * OUT_F + 4);
    };
    auto compute_group = [&]() {
        const float sf[8] = {sv0.x, sv0.y, sv0.z, sv0.w, sv1.x, sv1.y, sv1.z, sv1.w};
#pragma unroll
        for (int j = 0; j < 8; ++j) {
            float zb = 1024.0f + (float)((zraw_n >> SH[j]) & 15u);
            spk[j] = pkh2(sf[j], sf[j]);
            zpk[j] = pkh2(zb, zb);
        }
    };
    auto load_raws = [&](int kt) {
        const size_t off = (size_t)kt * BK * PCOLS;
        raw0 = (unsigned int)qwb[off];
        raw1 = (unsigned int)qwb[off + PCOLS];
    };
    auto stage_B = [&](int buf) {
        unsigned char* bb = smem + ABYTES + buf * BBYTES;
#pragma unroll
        for (int b = 0; b < 4; ++b) {
            const int jl = JLO[b], jh = jl + 2;
            unsigned int d  = __builtin_amdgcn_perm(raw1, raw0,
                                 (unsigned int)(((4 + b) << 16) | b));
            unsigned int lo = (d & 0x000F000Fu) | 0x64006400u;
            unsigned int hi = ((d >> 4) & 0x000F000Fu) | 0x64006400u;
            h2 wl = (__builtin_bit_cast(h2, lo) - zpk[jl]) * spk[jl];
            h2 wh = (__builtin_bit_cast(h2, hi) - zpk[jh]) * spk[jh];
            const int nl = pcol * 8 + jl, nh = pcol * 8 + jh;
            *(unsigned int*)(bb + nl * 128 + ((ob ^ jl ^ pc7) * 16) + sub) =
                __builtin_bit_cast(unsigned int, wl);
            *(unsigned int*)(bb + nh * 128 + ((ob ^ jh ^ pc7) * 16) + sub) =
                __builtin_bit_cast(unsigned int, wh);
        }
    };

    f32x4 acc[4][4];
#pragma unroll
    for (int mi = 0; mi < 4; ++mi)
#pragma unroll
        for (int ni = 0; ni < 4; ++ni)
            acc[mi][ni] = f32x4{0.f, 0.f, 0.f, 0.f};

    auto compute_tile = [&](int buf) {
        const unsigned char* ab = smem;
        const unsigned char* bb = smem + ABYTES + buf * BBYTES;
#pragma unroll
        for (int ks = 0; ks < 2; ++ks) {
            h8 a[4], bf[4];
#pragma unroll
            for (int mi = 0; mi < 4; ++mi) {
                int off = (wm * 64 + mi * 16 + l15) * 128
                        + (((ks * 4 + l45) ^ l7) * 16);
                a[mi] = *(const h8*)(ab + off);
            }
#pragma unroll
            for (int ni = 0; ni < 4; ++ni) {
                int off = (wn * 64 + ni * 16 + l15) * 128
                        + ((((ks * 4 + l45) ^ l7 ^ l3) ^ (2 * ni)) * 16);
                bf[ni] = *(const h8*)(bb + off);
            }
#pragma unroll
            for (int mi = 0; mi < 4; ++mi)
#pragma unroll
                for (int ni = 0; ni < 4; ++ni)
                    acc[mi][ni] = __builtin_amdgcn_mfma_f32_16x16x32_f16(
                        a[mi], bf[ni], acc[mi][ni], 0, 0, 0);
        }
    };

    load_A(0);
    load_raws(0);
    load_group(0);
    compute_group();
    write_A();
    stage_B(0);
    __syncthreads();

#pragma unroll 2
    for (int kt = 0; kt < NKT; ++kt) {
        const int cur = kt & 1;
        if (kt + 1 < NKT) {
            load_A(kt + 1);
            load_raws(kt + 1);
            if (((kt + 1) & 1) == 0) load_group((kt + 1) >> 1);
        }
        compute_tile(cur);
        if (kt + 1 < NKT) {
            if (((kt + 1) & 1) == 0) compute_group();
            stage_B(cur ^ 1);
        }
        __syncthreads();
        if (kt + 1 < NKT) write_A();
        __syncthreads();
    }

    const int orow0 = m0 + wm * 64 + l45 * 4;
    const int ocol0 = n0 + wn * 64 + l15;
    float bv[4];
#pragma unroll
    for (int ni = 0; ni < 4; ++ni)
        bv[ni] = BIAS[ocol0 + ni * 16];
#pragma unroll
    for (int mi = 0; mi < 4; ++mi)
#pragma unroll
        for (int ni = 0; ni < 4; ++ni)
#pragma unroll
            for (int r = 0; r < 4; ++r) {
                int row = orow0 + mi * 16 + r;
                int col = ocol0 + ni * 16;
                O[(size_t)row * OUT_F + col] = acc[mi][ni][r] + bv[ni];
            }
}

extern "C" void kernel_launch(void* const* d_in, const int* in_sizes, int n_in,
                              void* d_out, int out_size, void* d_ws, size_t ws_size,
                              hipStream_t stream) {
    const float* X  = (const float*)d_in[0];
    const int*   QW = (const int*)d_in[1];
    const int*   QZ = (const int*)d_in[2];
    const float* S  = (const float*)d_in[3];
    const float* Bi = (const float*)d_in[4];
    float*       O  = (float*)d_out;

    if (ws_size >= XSW_BYTES) {
        unsigned short* Xsw = (unsigned short*)d_ws;
        x_convert_kernel<<<dim3(TOKENS * IN_F / 8 / 256), dim3(256), 0, stream>>>(X, Xsw);
        awq_gemm_cv_kernel<<<dim3(8 * NTILES), dim3(512), LDSTOT, stream>>>(
            Xsw, QW, QZ, S, Bi, O);
    } else {
        awq_gemm_fb_kernel<<<dim3(8 * NTILES), dim3(512), 0, stream>>>(X, QW, QZ, S, Bi, O);
    }
}